// Round 7
// baseline (25.586 us; speedup 1.0000x reference)
//
#include <hip/hip_runtime.h>
#include <hip/hip_bf16.h>

// Problem: B=32, T=1024, D=512, x float32 (B,T,D) viewed flat as per-batch
// row-major M[D][T].  Row 0 = padding, rows 1..D-1 = signal.
//   norm[t]      = sum_{d=1..D-1} |M[d][t]|
//   one_minus[t] = 1 / (1 + exp(M[0][t] - norm[t]))
//   out[0][t]    = M[0][t] * (1 + |padding_amount|)
//   out[d][t]    = M[d][t] * one_minus[t]                 (d >= 1)
//
// R7 = R5 + NONTEMPORAL STORES (R6 retry; builtin needs a native vector
// type, not HIP_vector_type -> use ext_vector_type(4) for the store).
// Rationale: output is write-once/never-read; regular stores write-allocate
// in L2/L3 and evict the L3-resident input (R4 profile: FETCH 32.8 MB = half
// the input already served from cache).  `nt` stores stream the output past
// the caches, preserving input residency and L2 port bandwidth for reads.
//
// Geometry (identical to R5): block = 128 threads (2 waves), tile =
// 32 cols x 512 rows, per-thread cache 32 x float4, grid = 1024 blocks.

#define BB 32
#define TT 1024
#define DD 512

constexpr int TBC = 32;               // columns per block tile
constexpr int R   = 32;               // float4 rows per thread

typedef float f32x4 __attribute__((ext_vector_type(4)));

__global__ __launch_bounds__(128, 3) void padding_bottleneck_kernel(
    const float* __restrict__ x,
    const float* __restrict__ padding_amount,
    float* __restrict__ out)
{
    const int blk  = blockIdx.x;            // 0..1023
    const int b    = blk >> 5;              // batch
    const int ct   = blk & 31;              // 32-col tile within batch
    const int lane = threadIdx.x & 63;
    const int wv   = threadIdx.x >> 6;      // 0..1
    const int cg   = lane & 7;              // column group (4 cols, 16 B)
    const int rg   = lane >> 3;             // row group 0..7 (32 rows each)
    const int c0   = ct * TBC + cg * 4;
    const int r0   = wv * 256 + rg * R;

    const size_t base = (size_t)b * DD * TT + (size_t)r0 * TT + c0;
    const float* src = x + base;
    float*       dst = out + base;

    // ---- pass 1: load 32 float4 into registers, per-column |.| partials
    float4 v[R];
    float s0 = 0.f, s1 = 0.f, s2 = 0.f, s3 = 0.f;
#pragma unroll
    for (int j = 0; j < R; ++j) {
        v[j] = *reinterpret_cast<const float4*>(src + (size_t)j * TT);
        s0 += fabsf(v[j].x); s1 += fabsf(v[j].y);
        s2 += fabsf(v[j].z); s3 += fabsf(v[j].w);
    }

    __shared__ float4 psum4[2][8];
    __shared__ float4 padv4[8];

    const bool has_pad = (wv == 0 && rg == 0);   // j==0 is global row d=0
    if (has_pad) {
        s0 -= fabsf(v[0].x); s1 -= fabsf(v[0].y);
        s2 -= fabsf(v[0].z); s3 -= fabsf(v[0].w);
        padv4[cg] = v[0];
    }

    // ---- fold the 8 row-groups of this wave (lane bits 3..5)
    s0 += __shfl_xor(s0, 8);  s1 += __shfl_xor(s1, 8);
    s2 += __shfl_xor(s2, 8);  s3 += __shfl_xor(s3, 8);
    s0 += __shfl_xor(s0, 16); s1 += __shfl_xor(s1, 16);
    s2 += __shfl_xor(s2, 16); s3 += __shfl_xor(s3, 16);
    s0 += __shfl_xor(s0, 32); s1 += __shfl_xor(s1, 32);
    s2 += __shfl_xor(s2, 32); s3 += __shfl_xor(s3, 32);

    if (rg == 0) psum4[wv][cg] = make_float4(s0, s1, s2, s3);
    __syncthreads();

    // ---- per-column weight (2-wave combine)
    const float4 pa0 = psum4[0][cg];
    const float4 pa1 = psum4[1][cg];
    const float4 pv  = padv4[cg];
    const float om0 = 1.f / (1.f + __expf(pv.x - (pa0.x + pa1.x)));
    const float om1 = 1.f / (1.f + __expf(pv.y - (pa0.y + pa1.y)));
    const float om2 = 1.f / (1.f + __expf(pv.z - (pa0.z + pa1.z)));
    const float om3 = 1.f / (1.f + __expf(pv.w - (pa0.w + pa1.w)));
    const float scale = 1.f + fabsf(padding_amount[0]);

    // ---- pass 2: scale cached registers, nontemporal float4 stores
#pragma unroll
    for (int j = 0; j < R; ++j) {
        f32x4 o;
        if (has_pad && j == 0) {
            o.x = v[0].x * scale; o.y = v[0].y * scale;
            o.z = v[0].z * scale; o.w = v[0].w * scale;
        } else {
            o.x = v[j].x * om0; o.y = v[j].y * om1;
            o.z = v[j].z * om2; o.w = v[j].w * om3;
        }
        __builtin_nontemporal_store(o, reinterpret_cast<f32x4*>(dst + (size_t)j * TT));
    }
}

extern "C" void kernel_launch(void* const* d_in, const int* in_sizes, int n_in,
                              void* d_out, int out_size, void* d_ws, size_t ws_size,
                              hipStream_t stream)
{
    const float* x  = (const float*)d_in[0];
    const float* pa = (const float*)d_in[1];
    float* out      = (float*)d_out;

    // one block per (batch, 32-col tile): 32 * 32 = 1024 blocks, 128 thr each
    dim3 grid(BB * (TT / TBC));
    dim3 block(128);
    padding_bottleneck_kernel<<<grid, block, 0, stream>>>(x, pa, out);
}